// Round 5
// baseline (652.829 us; speedup 1.0000x reference)
//
#include <hip/hip_runtime.h>
#include <hip/hip_fp16.h>

#define N_ENTITY 64368
#define N_REL 40
#define DIM 128
#define N_BASES 8
#define N_EDGES 500000
#define BATCH 64
#define SEED_LEN 32
#define NROWS (BATCH * SEED_LEN)            // 2048
#define SCAN_NB ((N_ENTITY + 255) / 256)    // 252
#define NPAD (SCAN_NB * 256)                // 64512 (block-aligned entity count)

#define CAP 64                               // slot capacity per dst (Poisson(7.8), max~28)
#define OVF_CAP 4096                         // overflow list capacity (never hit in practice)
#define SCAT_BLOCKS ((N_EDGES + 255) / 256)  // 1954
#define CVT_BLOCKS 2048

// interleaved fp16 basis layout: basis16[e][dgrp][bpair][8]
//   halfs layout per 16B chunk: {b=2*bp: d0..d3, b=2*bp+1: d0..d3}
//   entity block = 1024 halfs (2KB); lane l32 owns 64B chunk at l32*32 halfs
//   (dims 4*l32..4*l32+3 for all 8 bases).

struct alignas(16) h8 { __half2 a, b, c, d; };

// ===========================================================================
// K1: fused {edge scatter into capacity-padded dst buckets} || {basis fp32 ->
// fp16 interleaved convert}. Disjoint block ranges, ONE dispatch.
// ===========================================================================
__global__ __launch_bounds__(256) void k_prep(
    const int* __restrict__ esrc, const int* __restrict__ edst,
    const int* __restrict__ etype, const float* __restrict__ basis,
    __half* __restrict__ basis16, int* __restrict__ cnt,
    int* __restrict__ novf, int* __restrict__ ovf, int* __restrict__ slots)
{
    int bid = blockIdx.x, tid = threadIdx.x;
    if (bid < SCAT_BLOCKS) {
        // ---- edge scatter: k = atomicAdd(cnt[dst]); slots[dst*CAP+k]=meta ----
        int e = bid * 256 + tid;
        if (e < N_EDGES) {
            int d = edst[e];
            int meta = esrc[e] * 64 + etype[e];      // src<2^17 -> meta<2^23
            int k = atomicAdd(&cnt[d], 1);
            if (k < CAP) {
                slots[(size_t)d * CAP + k] = meta;
            } else {                                  // statistically impossible;
                int o = atomicAdd(novf, 1);           // kept for correctness
                if (o < OVF_CAP) { ovf[2 * o] = d; ovf[2 * o + 1] = meta; }
            }
        }
    } else {
        // ---- basis convert: half-wave per entity, float4 reads, h8 writes ----
        int lane = tid & 63;
        int l32  = lane & 31;
        int hw   = lane >> 5;
        int wv   = ((bid - SCAT_BLOCKS) << 2) + (tid >> 6);   // wave id
        const size_t bstride = (size_t)N_ENTITY * DIM;

        for (int e2 = wv; 2 * e2 < N_ENTITY; e2 += (CVT_BLOCKS << 2)) {
            int e = 2 * e2 + hw;                      // entity for this half-wave
            const float* sp = basis + (size_t)e * DIM + (l32 << 2);
            __half* dp = basis16 + ((size_t)e << 10) + (l32 << 5);
            #pragma unroll
            for (int it = 0; it < 4; ++it) {
                float4 v0 = *(const float4*)(sp + (size_t)(2 * it)     * bstride);
                float4 v1 = *(const float4*)(sp + (size_t)(2 * it + 1) * bstride);
                h8 o;
                o.a = __floats2half2_rn(v0.x, v0.y);
                o.b = __floats2half2_rn(v0.z, v0.w);
                o.c = __floats2half2_rn(v1.x, v1.y);
                o.d = __floats2half2_rn(v1.z, v1.w);
                *(h8*)(dp + it * 8) = o;
            }
        }
    }
}

// ===========================================================================
// K2: dst-major gather. One wave per dst; half-wave per edge, 2 edges deep.
// Per edge per lane: 4x16B loads of the lane's 64B chunk (dims 4*l32..+3,
// all 8 bases) from LLC-resident basis16[src]; fp32 accumulate; fused
// mean + root + bias.
// ===========================================================================
__device__ __forceinline__ void acc_edge(
    const __half* __restrict__ p, float4 c0, float4 c1, float4& acc)
{
    h8 h0 = *(const h8*)(p + 0);
    h8 h1 = *(const h8*)(p + 8);
    h8 h2 = *(const h8*)(p + 16);
    h8 h3 = *(const h8*)(p + 24);
    float2 fa, fb, fc, fd;
    // it=0: bases 0,1
    fa = __half22float2(h0.a); fb = __half22float2(h0.b);
    fc = __half22float2(h0.c); fd = __half22float2(h0.d);
    acc.x += c0.x * fa.x + c0.y * fc.x;
    acc.y += c0.x * fa.y + c0.y * fc.y;
    acc.z += c0.x * fb.x + c0.y * fd.x;
    acc.w += c0.x * fb.y + c0.y * fd.y;
    // it=1: bases 2,3
    fa = __half22float2(h1.a); fb = __half22float2(h1.b);
    fc = __half22float2(h1.c); fd = __half22float2(h1.d);
    acc.x += c0.z * fa.x + c0.w * fc.x;
    acc.y += c0.z * fa.y + c0.w * fc.y;
    acc.z += c0.z * fb.x + c0.w * fd.x;
    acc.w += c0.z * fb.y + c0.w * fd.y;
    // it=2: bases 4,5
    fa = __half22float2(h2.a); fb = __half22float2(h2.b);
    fc = __half22float2(h2.c); fd = __half22float2(h2.d);
    acc.x += c1.x * fa.x + c1.y * fc.x;
    acc.y += c1.x * fa.y + c1.y * fc.y;
    acc.z += c1.x * fb.x + c1.y * fd.x;
    acc.w += c1.x * fb.y + c1.y * fd.y;
    // it=3: bases 6,7
    fa = __half22float2(h3.a); fb = __half22float2(h3.b);
    fc = __half22float2(h3.c); fd = __half22float2(h3.d);
    acc.x += c1.z * fa.x + c1.w * fc.x;
    acc.y += c1.z * fa.y + c1.w * fc.y;
    acc.z += c1.z * fb.x + c1.w * fd.x;
    acc.w += c1.z * fb.y + c1.w * fd.y;
}

__global__ __launch_bounds__(256) void k_gather16(
    const int* __restrict__ cnt, const int* __restrict__ novf,
    const int* __restrict__ ovf, const int* __restrict__ slots,
    const __half* __restrict__ basis16, const float* __restrict__ att,
    const float* __restrict__ root, const float* __restrict__ bias,
    float* __restrict__ agg)
{
    __shared__ float att_s[N_REL * N_BASES];
    int tid = threadIdx.x;
    for (int i = tid; i < N_REL * N_BASES; i += 256) att_s[i] = att[i];
    __syncthreads();

    int wid  = (int)((blockIdx.x * 256 + tid) >> 6);
    int lane = tid & 63;
    if (wid >= N_ENTITY) return;
    int half = lane >> 5;
    int l32  = lane & 31;

    int c = cnt[wid];
    int n = (c < CAP) ? c : CAP;
    const int* sl = slots + (size_t)wid * CAP;

    float4 acc = {0.f, 0.f, 0.f, 0.f};
    int j = 0;
    for (; j + 3 < n; j += 4) {                    // 2 edges per half-wave
        int m0 = sl[j], m1 = sl[j + 1], m2 = sl[j + 2], m3 = sl[j + 3];
        int mA = half ? m1 : m0;
        int mB = half ? m3 : m2;
        const __half* pA = basis16 + ((size_t)(mA >> 6) << 10) + (l32 << 5);
        const __half* pB = basis16 + ((size_t)(mB >> 6) << 10) + (l32 << 5);
        float4 cA0 = *(const float4*)(att_s + (mA & 63) * N_BASES);
        float4 cA1 = *(const float4*)(att_s + (mA & 63) * N_BASES + 4);
        float4 cB0 = *(const float4*)(att_s + (mB & 63) * N_BASES);
        float4 cB1 = *(const float4*)(att_s + (mB & 63) * N_BASES + 4);
        acc_edge(pA, cA0, cA1, acc);
        acc_edge(pB, cB0, cB1, acc);
    }
    for (; j < n; j += 2) {                        // tail: 1-2 edges
        int m0 = sl[j];
        bool has1 = (j + 1 < n);
        int m = half ? (has1 ? sl[j + 1] : m0) : m0;
        float sc = (half && !has1) ? 0.0f : 1.0f;
        const __half* p = basis16 + ((size_t)(m >> 6) << 10) + (l32 << 5);
        float4 c0 = *(const float4*)(att_s + (m & 63) * N_BASES);
        float4 c1 = *(const float4*)(att_s + (m & 63) * N_BASES + 4);
        c0.x *= sc; c0.y *= sc; c0.z *= sc; c0.w *= sc;
        c1.x *= sc; c1.y *= sc; c1.z *= sc; c1.w *= sc;
        acc_edge(p, c0, c1, acc);
    }
    if (c > CAP) {                                 // correctness path (p~0)
        int nov = *novf; if (nov > OVF_CAP) nov = OVF_CAP;
        for (int k = 0; k < nov; ++k) {
            if (ovf[2 * k] == wid) {
                int m = ovf[2 * k + 1];
                const __half* p = basis16 + ((size_t)(m >> 6) << 10) + (l32 << 5);
                float sc = half ? 0.0f : 1.0f;
                float4 c0 = *(const float4*)(att_s + (m & 63) * N_BASES);
                float4 c1 = *(const float4*)(att_s + (m & 63) * N_BASES + 4);
                c0.x *= sc; c0.y *= sc; c0.z *= sc; c0.w *= sc;
                c1.x *= sc; c1.y *= sc; c1.z *= sc; c1.w *= sc;
                acc_edge(p, c0, c1, acc);
            }
        }
    }

    acc.x += __shfl_xor(acc.x, 32, 64);
    acc.y += __shfl_xor(acc.y, 32, 64);
    acc.z += __shfl_xor(acc.z, 32, 64);
    acc.w += __shfl_xor(acc.w, 32, 64);

    if (half == 0) {
        float inv = 1.0f / fmaxf((float)c, 1.0f);
        int o = wid * DIM + l32 * 4;
        float4 r  = *(const float4*)(root + o);
        float4 bb = *(const float4*)(bias + l32 * 4);
        float4 outv;
        outv.x = acc.x * inv + r.x + bb.x;
        outv.y = acc.y * inv + r.y + bb.y;
        outv.z = acc.z * inv + r.z + bb.z;
        outv.w = acc.w * inv + r.w + bb.w;
        *(float4*)(agg + o) = outv;
    }
}

// ===========================================================================
// Fused attention: T = tanh(H@A) in registers, e = T@b, softmax, u.
// One block per batch.
// ===========================================================================
__global__ __launch_bounds__(256) void k_attn(
    const int* __restrict__ seed_ids, const float* __restrict__ nodes,
    const float* __restrict__ A, const float* __restrict__ Bv,
    float* __restrict__ uT)
{
    __shared__ float Hs[SEED_LEN * DIM];   // 16 KB
    __shared__ float ew[SEED_LEN];
    __shared__ float attw[SEED_LEN];

    int b = blockIdx.x, tid = threadIdx.x;

    for (int i = tid; i < SEED_LEN * DIM; i += 256) {
        int ss = i >> 7, d = i & 127;
        Hs[i] = nodes[(size_t)seed_ids[b * SEED_LEN + ss] * DIM + d];
    }
    __syncthreads();

    int jx = tid & 31;          // cols jx*4..+3
    int iy = tid >> 5;          // rows iy*4..+3
    float acc[4][4] = {{0,0,0,0},{0,0,0,0},{0,0,0,0},{0,0,0,0}};

    for (int d = 0; d < DIM; ++d) {
        const float4 a4 = *(const float4*)(A + d * DIM + jx * 4);
        float h0 = Hs[(iy * 4 + 0) * DIM + d];
        float h1 = Hs[(iy * 4 + 1) * DIM + d];
        float h2 = Hs[(iy * 4 + 2) * DIM + d];
        float h3 = Hs[(iy * 4 + 3) * DIM + d];
        acc[0][0] += h0 * a4.x; acc[0][1] += h0 * a4.y;
        acc[0][2] += h0 * a4.z; acc[0][3] += h0 * a4.w;
        acc[1][0] += h1 * a4.x; acc[1][1] += h1 * a4.y;
        acc[1][2] += h1 * a4.z; acc[1][3] += h1 * a4.w;
        acc[2][0] += h2 * a4.x; acc[2][1] += h2 * a4.y;
        acc[2][2] += h2 * a4.z; acc[2][3] += h2 * a4.w;
        acc[3][0] += h3 * a4.x; acc[3][1] += h3 * a4.y;
        acc[3][2] += h3 * a4.z; acc[3][3] += h3 * a4.w;
    }

    const float4 bv = *(const float4*)(Bv + jx * 4);
    #pragma unroll
    for (int i = 0; i < 4; ++i) {
        float pe = tanhf(acc[i][0]) * bv.x + tanhf(acc[i][1]) * bv.y
                 + tanhf(acc[i][2]) * bv.z + tanhf(acc[i][3]) * bv.w;
        pe += __shfl_xor(pe, 1, 64);
        pe += __shfl_xor(pe, 2, 64);
        pe += __shfl_xor(pe, 4, 64);
        pe += __shfl_xor(pe, 8, 64);
        pe += __shfl_xor(pe, 16, 64);
        if (jx == 0) ew[iy * 4 + i] = pe;
    }
    __syncthreads();

    if (tid == 0) {
        float mx = -1e30f;
        for (int k = 0; k < SEED_LEN; ++k) mx = fmaxf(mx, ew[k]);
        float ssum = 0.0f;
        for (int k = 0; k < SEED_LEN; ++k) {
            float v = expf(ew[k] - mx);
            attw[k] = v; ssum += v;
        }
        float inv = 1.0f / ssum;
        for (int k = 0; k < SEED_LEN; ++k) attw[k] *= inv;
    }
    __syncthreads();

    if (tid < DIM) {
        float a = 0.0f;
        for (int k = 0; k < SEED_LEN; ++k) a += attw[k] * Hs[k * DIM + tid];
        uT[tid * BATCH + b] = a;
    }
}

// ===========================================================================
// Scores: out[b][n] = u[b]·nodes[n] + out_bias[n]
// ===========================================================================
__global__ __launch_bounds__(256) void k_scores(
    const float* __restrict__ nodes, const float* __restrict__ uT,
    const float* __restrict__ out_bias, float* __restrict__ out)
{
    __shared__ float Nl[DIM * 65];

    int tid = threadIdx.x;
    int n0  = blockIdx.x * 64;

    for (int i = tid; i < 64 * DIM; i += 256) {
        int n = i >> 7, d = i & 127;
        int gn = n0 + n;
        Nl[d * 65 + n] = (gn < N_ENTITY) ? nodes[(size_t)gn * DIM + d] : 0.0f;
    }
    __syncthreads();

    int w    = __builtin_amdgcn_readfirstlane(tid >> 6);
    int lane = tid & 63;
    int b0   = w * 16;

    float acc[16];
    #pragma unroll
    for (int k = 0; k < 16; ++k) acc[k] = 0.0f;

    #pragma unroll 4
    for (int d = 0; d < DIM; ++d) {
        float nv = Nl[d * 65 + lane];
        const float* up = uT + d * BATCH + b0;
        #pragma unroll
        for (int k = 0; k < 16; ++k) acc[k] += up[k] * nv;
    }

    int gn = n0 + lane;
    if (gn < N_ENTITY) {
        float ob = out_bias[gn];
        #pragma unroll
        for (int k = 0; k < 16; ++k)
            out[(size_t)(b0 + k) * N_ENTITY + gn] = acc[k] + ob;
    }
}

// ===========================================================================
// FALLBACK PATH (tiny ws): dst counting sort + fp32 gather.
// ===========================================================================
__global__ __launch_bounds__(256) void k_histF(
    const int* __restrict__ edst, int* __restrict__ hist)
{
    int e = blockIdx.x * 256 + threadIdx.x;
    if (e < N_EDGES) atomicAdd(&hist[edst[e]], 1);
}

__global__ __launch_bounds__(256) void k_scan1F(
    const int* __restrict__ hist, int* __restrict__ ptr,
    int* __restrict__ partial)
{
    __shared__ int s[256];
    int tid = threadIdx.x;
    int gid = blockIdx.x * 256 + tid;
    int v = hist[gid];
    s[tid] = v;
    __syncthreads();
    for (int off = 1; off < 256; off <<= 1) {
        int t = (tid >= off) ? s[tid - off] : 0;
        __syncthreads();
        s[tid] += t;
        __syncthreads();
    }
    ptr[gid] = s[tid] - v;
    if (tid == 255) partial[blockIdx.x] = s[255];
}

__global__ __launch_bounds__(256) void k_scan23F(
    int* __restrict__ ptr, const int* __restrict__ partial,
    int* __restrict__ work)
{
    __shared__ int s[256];
    int tid = threadIdx.x;
    int c   = blockIdx.x;
    int sum = 0;
    for (int k = tid; k < c; k += 256) sum += partial[k];
    s[tid] = sum;
    __syncthreads();
    for (int off = 128; off > 0; off >>= 1) {
        if (tid < off) s[tid] += s[tid + off];
        __syncthreads();
    }
    int p = ptr[c * 256 + tid] + s[0];
    ptr[c * 256 + tid]  = p;
    work[c * 256 + tid] = p;
}

__global__ __launch_bounds__(256) void k_scatterF(
    const int* __restrict__ esrc, const int* __restrict__ edst,
    const int* __restrict__ etype, int* __restrict__ work,
    int* __restrict__ meta)
{
    int e = blockIdx.x * 256 + threadIdx.x;
    if (e < N_EDGES) {
        int pos = atomicAdd(&work[edst[e]], 1);
        meta[pos] = esrc[e] * 64 + etype[e];
    }
}

#define ACC8(C0, C1, V0, V1, V2, V3, V4, V5, V6, V7)                         \
    acc.x += C0.x*V0.x + C0.y*V1.x + C0.z*V2.x + C0.w*V3.x                   \
           + C1.x*V4.x + C1.y*V5.x + C1.z*V6.x + C1.w*V7.x;                  \
    acc.y += C0.x*V0.y + C0.y*V1.y + C0.z*V2.y + C0.w*V3.y                   \
           + C1.x*V4.y + C1.y*V5.y + C1.z*V6.y + C1.w*V7.y;                  \
    acc.z += C0.x*V0.z + C0.y*V1.z + C0.z*V2.z + C0.w*V3.z                   \
           + C1.x*V4.z + C1.y*V5.z + C1.z*V6.z + C1.w*V7.z;                  \
    acc.w += C0.x*V0.w + C0.y*V1.w + C0.z*V2.w + C0.w*V3.w                   \
           + C1.x*V4.w + C1.y*V5.w + C1.z*V6.w + C1.w*V7.w;

__global__ __launch_bounds__(256) void k_gatherF(
    const int* __restrict__ ptr, const int* __restrict__ hist,
    const int* __restrict__ meta, const float* __restrict__ basis,
    const float* __restrict__ att, const float* __restrict__ root,
    const float* __restrict__ bias, float* __restrict__ agg)
{
    __shared__ float att_s[N_REL * N_BASES];
    int tid = threadIdx.x;
    for (int i = tid; i < N_REL * N_BASES; i += 256) att_s[i] = att[i];
    __syncthreads();

    int wid  = (int)((blockIdx.x * 256 + tid) >> 6);
    int lane = tid & 63;
    if (wid >= N_ENTITY) return;

    int half = lane >> 5;
    int l32  = lane & 31;
    int p   = ptr[wid];
    int cnt = hist[wid];
    const size_t bstride = (size_t)N_ENTITY * DIM;

    float4 acc = {0.f, 0.f, 0.f, 0.f};
    int j = 0;
    for (; j < cnt; j += 2) {
        int m0 = meta[p + j];
        bool has1 = (j + 1 < cnt);
        int m1 = has1 ? meta[p + j + 1] : m0;
        int m = half ? m1 : m0;
        float sc = (half && !has1) ? 0.0f : 1.0f;
        const float* bA = basis + (size_t)(m >> 6) * DIM + l32 * 4;
        float4 a0 = *(const float4*)(bA + 0 * bstride);
        float4 a1 = *(const float4*)(bA + 1 * bstride);
        float4 a2 = *(const float4*)(bA + 2 * bstride);
        float4 a3 = *(const float4*)(bA + 3 * bstride);
        float4 a4 = *(const float4*)(bA + 4 * bstride);
        float4 a5 = *(const float4*)(bA + 5 * bstride);
        float4 a6 = *(const float4*)(bA + 6 * bstride);
        float4 a7 = *(const float4*)(bA + 7 * bstride);
        float4 c0 = *(const float4*)(att_s + (m & 63) * N_BASES);
        float4 c1 = *(const float4*)(att_s + (m & 63) * N_BASES + 4);
        c0.x *= sc; c0.y *= sc; c0.z *= sc; c0.w *= sc;
        c1.x *= sc; c1.y *= sc; c1.z *= sc; c1.w *= sc;
        ACC8(c0, c1, a0, a1, a2, a3, a4, a5, a6, a7)
    }

    acc.x += __shfl_xor(acc.x, 32, 64);
    acc.y += __shfl_xor(acc.y, 32, 64);
    acc.z += __shfl_xor(acc.z, 32, 64);
    acc.w += __shfl_xor(acc.w, 32, 64);

    if (half == 0) {
        float inv = 1.0f / fmaxf((float)cnt, 1.0f);
        int o = wid * DIM + l32 * 4;
        float4 r  = *(const float4*)(root + o);
        float4 bb = *(const float4*)(bias + l32 * 4);
        float4 outv;
        outv.x = acc.x * inv + r.x + bb.x;
        outv.y = acc.y * inv + r.y + bb.y;
        outv.z = acc.z * inv + r.z + bb.z;
        outv.w = acc.w * inv + r.w + bb.w;
        *(float4*)(agg + o) = outv;
    }
}

// ===========================================================================
extern "C" void kernel_launch(void* const* d_in, const int* in_sizes, int n_in,
                              void* d_out, int out_size, void* d_ws, size_t ws_size,
                              hipStream_t stream)
{
    const int*   seed_ids  = (const int*)d_in[0];
    const int*   esrc      = (const int*)d_in[1];
    const int*   edst      = (const int*)d_in[2];
    const int*   etype     = (const int*)d_in[3];
    const float* basis     = (const float*)d_in[4];
    const float* att       = (const float*)d_in[5];
    const float* root      = (const float*)d_in[6];
    const float* rgcn_bias = (const float*)d_in[7];
    const float* attn_a    = (const float*)d_in[8];
    const float* attn_b    = (const float*)d_in[9];
    const float* out_bias  = (const float*)d_in[10];
    float* out = (float*)d_out;

    const size_t AGG_F  = (size_t)N_ENTITY * DIM;        // 8,239,104 words
    const size_t B16_W  = (size_t)N_ENTITY * 512;        // fp16 basis16 in words
    const size_t SLOT_W = (size_t)NPAD * CAP;            // 4,128,768

    const size_t main_words = AGG_F + B16_W + NPAD + 16 + 2 * OVF_CAP
                            + SLOT_W + 2 * BATCH * DIM + 64;
    bool big = ws_size >= main_words * 4;

    if (big) {
        float*  agg     = (float*)d_ws;
        __half* basis16 = (__half*)(agg + AGG_F);
        int*    cnt     = (int*)(agg + AGG_F + B16_W);
        int*    novf    = cnt + NPAD;
        int*    ovf     = novf + 16;
        int*    slots   = ovf + 2 * OVF_CAP;
        float*  uT      = (float*)(slots + SLOT_W);

        hipMemsetAsync(cnt, 0, (NPAD + 16) * sizeof(int), stream);
        k_prep<<<SCAT_BLOCKS + CVT_BLOCKS, 256, 0, stream>>>(
            esrc, edst, etype, basis, basis16, cnt, novf, ovf, slots);
        k_gather16<<<(N_ENTITY * 64 + 255) / 256, 256, 0, stream>>>(
            cnt, novf, ovf, slots, basis16, att, root, rgcn_bias, agg);
        k_attn<<<BATCH, 256, 0, stream>>>(seed_ids, agg, attn_a, attn_b, uT);
        k_scores<<<(N_ENTITY + 63) / 64, 256, 0, stream>>>(agg, uT, out_bias, out);
    } else {
        // fallback: dst counting-sort + fp32 gather
        float* agg   = (float*)d_ws;
        int*   hist  = (int*)(agg + AGG_F);     // NPAD
        int*   ptr   = hist + NPAD;
        int*   work  = ptr + NPAD;
        int*   part  = work + NPAD;             // 256
        int*   meta  = part + 256;              // N_EDGES
        float* uT    = (float*)(meta + N_EDGES);

        hipMemsetAsync(hist, 0, NPAD * sizeof(int), stream);
        k_histF<<<(N_EDGES + 255) / 256, 256, 0, stream>>>(edst, hist);
        k_scan1F<<<SCAN_NB, 256, 0, stream>>>(hist, ptr, part);
        k_scan23F<<<SCAN_NB, 256, 0, stream>>>(ptr, part, work);
        k_scatterF<<<(N_EDGES + 255) / 256, 256, 0, stream>>>(
            esrc, edst, etype, work, meta);
        k_gatherF<<<(N_ENTITY * 64 + 255) / 256, 256, 0, stream>>>(
            ptr, hist, meta, basis, att, root, rgcn_bias, agg);
        k_attn<<<BATCH, 256, 0, stream>>>(seed_ids, agg, attn_a, attn_b, uT);
        k_scores<<<(N_ENTITY + 63) / 64, 256, 0, stream>>>(agg, uT, out_bias, out);
    }
}

// Round 6
// 638.810 us; speedup vs baseline: 1.0219x; 1.0219x over previous
//
#include <hip/hip_runtime.h>
#include <hip/hip_fp16.h>

#define N_ENTITY 64368
#define N_REL 40
#define DIM 128
#define N_BASES 8
#define N_EDGES 500000
#define BATCH 64
#define SEED_LEN 32
#define NROWS (BATCH * SEED_LEN)            // 2048
#define SCAN_NB ((N_ENTITY + 255) / 256)    // 252
#define NPAD (SCAN_NB * 256)                // 64512 (block-aligned entity count)

#define CAP 64                               // slot capacity per dst (Poisson(7.8), max~28)
#define OVF_CAP 4096                         // overflow list capacity (never hit in practice)
#define SCAT4_BLOCKS ((N_EDGES / 4 + 255) / 256)   // 489 (4 edges/thread)
#define CVT_BLOCKS 2048

// interleaved fp16 basis layout: basis16[e] is a 2KB block of 1024 halfs:
//   chunk g (64B, g=0..31): dims 4g..4g+3 for all 8 bases, as 4 quads (16B):
//   quad q: {base 2q: d0..d3, base 2q+1: d0..d3}.
//   Gather view: lane l reads 32B at halfs [e*1024 + l*16, +16):
//   = quads {2*(l&1), 2*(l&1)+1} of chunk l>>1
//   = bases {4p..4p+3} (p=l&1) x dims {4g..4g+3} (g=l>>1).

struct alignas(16) h8 { __half2 a, b, c, d; };

// ===========================================================================
// K1: fused {edge scatter into capacity-padded dst buckets, 4 edges/thread}
// || {basis fp32 -> fp16 interleaved convert}. Disjoint block ranges.
// ===========================================================================
__device__ __forceinline__ void scat1(
    int s, int d, int y, int* __restrict__ cnt, int* __restrict__ novf,
    int* __restrict__ ovf, int* __restrict__ slots)
{
    int meta = s * 64 + y;                        // src<2^17 -> meta<2^23
    int k = atomicAdd(&cnt[d], 1);
    if (k < CAP) {
        slots[(size_t)d * CAP + k] = meta;
    } else {                                      // statistically impossible
        int o = atomicAdd(novf, 1);
        if (o < OVF_CAP) { ovf[2 * o] = d; ovf[2 * o + 1] = meta; }
    }
}

__global__ __launch_bounds__(256) void k_prep(
    const int* __restrict__ esrc, const int* __restrict__ edst,
    const int* __restrict__ etype, const float* __restrict__ basis,
    __half* __restrict__ basis16, int* __restrict__ cnt,
    int* __restrict__ novf, int* __restrict__ ovf, int* __restrict__ slots)
{
    int bid = blockIdx.x, tid = threadIdx.x;
    if (bid < SCAT4_BLOCKS) {
        // ---- edge scatter: 4 edges per thread, int4 loads ----
        int e4 = (bid * 256 + tid) * 4;
        if (e4 < N_EDGES) {                       // N_EDGES % 4 == 0
            int4 s4 = *(const int4*)(esrc + e4);
            int4 d4 = *(const int4*)(edst + e4);
            int4 y4 = *(const int4*)(etype + e4);
            scat1(s4.x, d4.x, y4.x, cnt, novf, ovf, slots);
            scat1(s4.y, d4.y, y4.y, cnt, novf, ovf, slots);
            scat1(s4.z, d4.z, y4.z, cnt, novf, ovf, slots);
            scat1(s4.w, d4.w, y4.w, cnt, novf, ovf, slots);
        }
    } else {
        // ---- basis convert: half-wave per entity, float4 reads, h8 writes ----
        int lane = tid & 63;
        int l32  = lane & 31;
        int hw   = lane >> 5;
        int wv   = ((bid - SCAT4_BLOCKS) << 2) + (tid >> 6);   // wave id
        const size_t bstride = (size_t)N_ENTITY * DIM;

        for (int e2 = wv; 2 * e2 < N_ENTITY; e2 += (CVT_BLOCKS << 2)) {
            int e = 2 * e2 + hw;                  // entity for this half-wave
            if (e >= N_ENTITY) continue;
            const float* sp = basis + (size_t)e * DIM + (l32 << 2);
            __half* dp = basis16 + ((size_t)e << 10) + (l32 << 5);
            #pragma unroll
            for (int it = 0; it < 4; ++it) {
                float4 v0 = *(const float4*)(sp + (size_t)(2 * it)     * bstride);
                float4 v1 = *(const float4*)(sp + (size_t)(2 * it + 1) * bstride);
                h8 o;
                o.a = __floats2half2_rn(v0.x, v0.y);
                o.b = __floats2half2_rn(v0.z, v0.w);
                o.c = __floats2half2_rn(v1.x, v1.y);
                o.d = __floats2half2_rn(v1.z, v1.w);
                *(h8*)(dp + it * 8) = o;
            }
        }
    }
}

// ===========================================================================
// K2: dst-major gather. One WAVE per dst, FULL WAVE per edge, 4 edges in
// flight. Lane l: 32B = bases 4p..4p+3 (p=l&1) x dims 4g..4g+3 (g=l>>1).
// Pair-combine with shfl_xor(1); fused mean + root + bias.
// ===========================================================================
__device__ __forceinline__ void acc_edge2(
    const h8& q0, const h8& q1, float4 c, float4& acc)
{
    float2 f;
    f = __half22float2(q0.a); acc.x += c.x * f.x; acc.y += c.x * f.y;
    f = __half22float2(q0.b); acc.z += c.x * f.x; acc.w += c.x * f.y;
    f = __half22float2(q0.c); acc.x += c.y * f.x; acc.y += c.y * f.y;
    f = __half22float2(q0.d); acc.z += c.y * f.x; acc.w += c.y * f.y;
    f = __half22float2(q1.a); acc.x += c.z * f.x; acc.y += c.z * f.y;
    f = __half22float2(q1.b); acc.z += c.z * f.x; acc.w += c.z * f.y;
    f = __half22float2(q1.c); acc.x += c.w * f.x; acc.y += c.w * f.y;
    f = __half22float2(q1.d); acc.z += c.w * f.x; acc.w += c.w * f.y;
}

__global__ __launch_bounds__(256) void k_gather16(
    const int* __restrict__ cnt, const int* __restrict__ novf,
    const int* __restrict__ ovf, const int* __restrict__ slots,
    const __half* __restrict__ basis16, const float* __restrict__ att,
    const float* __restrict__ root, const float* __restrict__ bias,
    float* __restrict__ agg)
{
    __shared__ float att_s[N_REL * N_BASES];
    int tid = threadIdx.x;
    for (int i = tid; i < N_REL * N_BASES; i += 256) att_s[i] = att[i];
    __syncthreads();

    int wid  = (int)((blockIdx.x * 256 + tid) >> 6);
    int lane = tid & 63;
    if (wid >= N_ENTITY) return;
    int par = lane & 1;
    const int loff = lane << 4;                   // 16 halfs per lane

    int c = cnt[wid];
    int n = (c < CAP) ? c : CAP;
    const int* sl = slots + (size_t)wid * CAP;

    float4 acc = {0.f, 0.f, 0.f, 0.f};
    int j = 0;
    for (; j + 3 < n; j += 4) {                   // 4 edges in flight
        int4 mm = *(const int4*)(sl + j);
        const __half* p0 = basis16 + ((size_t)(mm.x >> 6) << 10) + loff;
        const __half* p1 = basis16 + ((size_t)(mm.y >> 6) << 10) + loff;
        const __half* p2 = basis16 + ((size_t)(mm.z >> 6) << 10) + loff;
        const __half* p3 = basis16 + ((size_t)(mm.w >> 6) << 10) + loff;
        h8 a0 = *(const h8*)(p0);  h8 b0 = *(const h8*)(p0 + 8);
        h8 a1 = *(const h8*)(p1);  h8 b1 = *(const h8*)(p1 + 8);
        h8 a2 = *(const h8*)(p2);  h8 b2 = *(const h8*)(p2 + 8);
        h8 a3 = *(const h8*)(p3);  h8 b3 = *(const h8*)(p3 + 8);
        float4 c0 = *(const float4*)(att_s + (mm.x & 63) * N_BASES + par * 4);
        float4 c1 = *(const float4*)(att_s + (mm.y & 63) * N_BASES + par * 4);
        float4 c2 = *(const float4*)(att_s + (mm.z & 63) * N_BASES + par * 4);
        float4 c3 = *(const float4*)(att_s + (mm.w & 63) * N_BASES + par * 4);
        acc_edge2(a0, b0, c0, acc);
        acc_edge2(a1, b1, c1, acc);
        acc_edge2(a2, b2, c2, acc);
        acc_edge2(a3, b3, c3, acc);
    }
    for (; j < n; ++j) {                          // tail: full wave per edge
        int m = sl[j];
        const __half* p = basis16 + ((size_t)(m >> 6) << 10) + loff;
        h8 q0 = *(const h8*)(p);  h8 q1 = *(const h8*)(p + 8);
        float4 cc = *(const float4*)(att_s + (m & 63) * N_BASES + par * 4);
        acc_edge2(q0, q1, cc, acc);
    }
    if (c > CAP) {                                // correctness path (p~0)
        int nov = *novf; if (nov > OVF_CAP) nov = OVF_CAP;
        for (int k = 0; k < nov; ++k) {
            if (ovf[2 * k] == wid) {
                int m = ovf[2 * k + 1];
                const __half* p = basis16 + ((size_t)(m >> 6) << 10) + loff;
                h8 q0 = *(const h8*)(p);  h8 q1 = *(const h8*)(p + 8);
                float4 cc = *(const float4*)(att_s + (m & 63) * N_BASES + par * 4);
                acc_edge2(q0, q1, cc, acc);
            }
        }
    }

    // combine lane pair: even lane had bases 0-3, odd had 4-7
    acc.x += __shfl_xor(acc.x, 1, 64);
    acc.y += __shfl_xor(acc.y, 1, 64);
    acc.z += __shfl_xor(acc.z, 1, 64);
    acc.w += __shfl_xor(acc.w, 1, 64);

    // write: dims 4g..4g+3; even lane writes (d0,d1), odd writes (d2,d3)
    float inv = 1.0f / fmaxf((float)c, 1.0f);
    int dof = ((lane >> 1) << 2) + par * 2;
    int o = wid * DIM + dof;
    float2 r  = *(const float2*)(root + o);
    float2 bb = *(const float2*)(bias + dof);
    float2 outv;
    float vx = par ? acc.z : acc.x;
    float vy = par ? acc.w : acc.y;
    outv.x = vx * inv + r.x + bb.x;
    outv.y = vy * inv + r.y + bb.y;
    *(float2*)(agg + o) = outv;
}

// ===========================================================================
// Fused attention: T = tanh(H@A) in registers, e = T@b, softmax, u.
// One block per batch.
// ===========================================================================
__global__ __launch_bounds__(256) void k_attn(
    const int* __restrict__ seed_ids, const float* __restrict__ nodes,
    const float* __restrict__ A, const float* __restrict__ Bv,
    float* __restrict__ uT)
{
    __shared__ float Hs[SEED_LEN * DIM];   // 16 KB
    __shared__ float ew[SEED_LEN];
    __shared__ float attw[SEED_LEN];

    int b = blockIdx.x, tid = threadIdx.x;

    for (int i = tid; i < SEED_LEN * DIM; i += 256) {
        int ss = i >> 7, d = i & 127;
        Hs[i] = nodes[(size_t)seed_ids[b * SEED_LEN + ss] * DIM + d];
    }
    __syncthreads();

    int jx = tid & 31;          // cols jx*4..+3
    int iy = tid >> 5;          // rows iy*4..+3
    float acc[4][4] = {{0,0,0,0},{0,0,0,0},{0,0,0,0},{0,0,0,0}};

    for (int d = 0; d < DIM; ++d) {
        const float4 a4 = *(const float4*)(A + d * DIM + jx * 4);
        float h0 = Hs[(iy * 4 + 0) * DIM + d];
        float h1 = Hs[(iy * 4 + 1) * DIM + d];
        float h2 = Hs[(iy * 4 + 2) * DIM + d];
        float h3 = Hs[(iy * 4 + 3) * DIM + d];
        acc[0][0] += h0 * a4.x; acc[0][1] += h0 * a4.y;
        acc[0][2] += h0 * a4.z; acc[0][3] += h0 * a4.w;
        acc[1][0] += h1 * a4.x; acc[1][1] += h1 * a4.y;
        acc[1][2] += h1 * a4.z; acc[1][3] += h1 * a4.w;
        acc[2][0] += h2 * a4.x; acc[2][1] += h2 * a4.y;
        acc[2][2] += h2 * a4.z; acc[2][3] += h2 * a4.w;
        acc[3][0] += h3 * a4.x; acc[3][1] += h3 * a4.y;
        acc[3][2] += h3 * a4.z; acc[3][3] += h3 * a4.w;
    }

    const float4 bv = *(const float4*)(Bv + jx * 4);
    #pragma unroll
    for (int i = 0; i < 4; ++i) {
        float pe = tanhf(acc[i][0]) * bv.x + tanhf(acc[i][1]) * bv.y
                 + tanhf(acc[i][2]) * bv.z + tanhf(acc[i][3]) * bv.w;
        pe += __shfl_xor(pe, 1, 64);
        pe += __shfl_xor(pe, 2, 64);
        pe += __shfl_xor(pe, 4, 64);
        pe += __shfl_xor(pe, 8, 64);
        pe += __shfl_xor(pe, 16, 64);
        if (jx == 0) ew[iy * 4 + i] = pe;
    }
    __syncthreads();

    if (tid == 0) {
        float mx = -1e30f;
        for (int k = 0; k < SEED_LEN; ++k) mx = fmaxf(mx, ew[k]);
        float ssum = 0.0f;
        for (int k = 0; k < SEED_LEN; ++k) {
            float v = expf(ew[k] - mx);
            attw[k] = v; ssum += v;
        }
        float inv = 1.0f / ssum;
        for (int k = 0; k < SEED_LEN; ++k) attw[k] *= inv;
    }
    __syncthreads();

    if (tid < DIM) {
        float a = 0.0f;
        for (int k = 0; k < SEED_LEN; ++k) a += attw[k] * Hs[k * DIM + tid];
        uT[tid * BATCH + b] = a;
    }
}

// ===========================================================================
// Scores: out[b][n] = u[b]·nodes[n] + out_bias[n]
// ===========================================================================
__global__ __launch_bounds__(256) void k_scores(
    const float* __restrict__ nodes, const float* __restrict__ uT,
    const float* __restrict__ out_bias, float* __restrict__ out)
{
    __shared__ float Nl[DIM * 65];

    int tid = threadIdx.x;
    int n0  = blockIdx.x * 64;

    for (int i = tid; i < 64 * DIM; i += 256) {
        int n = i >> 7, d = i & 127;
        int gn = n0 + n;
        Nl[d * 65 + n] = (gn < N_ENTITY) ? nodes[(size_t)gn * DIM + d] : 0.0f;
    }
    __syncthreads();

    int w    = __builtin_amdgcn_readfirstlane(tid >> 6);
    int lane = tid & 63;
    int b0   = w * 16;

    float acc[16];
    #pragma unroll
    for (int k = 0; k < 16; ++k) acc[k] = 0.0f;

    #pragma unroll 4
    for (int d = 0; d < DIM; ++d) {
        float nv = Nl[d * 65 + lane];
        const float* up = uT + d * BATCH + b0;
        #pragma unroll
        for (int k = 0; k < 16; ++k) acc[k] += up[k] * nv;
    }

    int gn = n0 + lane;
    if (gn < N_ENTITY) {
        float ob = out_bias[gn];
        #pragma unroll
        for (int k = 0; k < 16; ++k)
            out[(size_t)(b0 + k) * N_ENTITY + gn] = acc[k] + ob;
    }
}

// ===========================================================================
// FALLBACK PATH (tiny ws): dst counting sort + fp32 gather.
// ===========================================================================
__global__ __launch_bounds__(256) void k_histF(
    const int* __restrict__ edst, int* __restrict__ hist)
{
    int e = blockIdx.x * 256 + threadIdx.x;
    if (e < N_EDGES) atomicAdd(&hist[edst[e]], 1);
}

__global__ __launch_bounds__(256) void k_scan1F(
    const int* __restrict__ hist, int* __restrict__ ptr,
    int* __restrict__ partial)
{
    __shared__ int s[256];
    int tid = threadIdx.x;
    int gid = blockIdx.x * 256 + tid;
    int v = hist[gid];
    s[tid] = v;
    __syncthreads();
    for (int off = 1; off < 256; off <<= 1) {
        int t = (tid >= off) ? s[tid - off] : 0;
        __syncthreads();
        s[tid] += t;
        __syncthreads();
    }
    ptr[gid] = s[tid] - v;
    if (tid == 255) partial[blockIdx.x] = s[255];
}

__global__ __launch_bounds__(256) void k_scan23F(
    int* __restrict__ ptr, const int* __restrict__ partial,
    int* __restrict__ work)
{
    __shared__ int s[256];
    int tid = threadIdx.x;
    int c   = blockIdx.x;
    int sum = 0;
    for (int k = tid; k < c; k += 256) sum += partial[k];
    s[tid] = sum;
    __syncthreads();
    for (int off = 128; off > 0; off >>= 1) {
        if (tid < off) s[tid] += s[tid + off];
        __syncthreads();
    }
    int p = ptr[c * 256 + tid] + s[0];
    ptr[c * 256 + tid]  = p;
    work[c * 256 + tid] = p;
}

__global__ __launch_bounds__(256) void k_scatterF(
    const int* __restrict__ esrc, const int* __restrict__ edst,
    const int* __restrict__ etype, int* __restrict__ work,
    int* __restrict__ meta)
{
    int e = blockIdx.x * 256 + threadIdx.x;
    if (e < N_EDGES) {
        int pos = atomicAdd(&work[edst[e]], 1);
        meta[pos] = esrc[e] * 64 + etype[e];
    }
}

#define ACC8(C0, C1, V0, V1, V2, V3, V4, V5, V6, V7)                         \
    acc.x += C0.x*V0.x + C0.y*V1.x + C0.z*V2.x + C0.w*V3.x                   \
           + C1.x*V4.x + C1.y*V5.x + C1.z*V6.x + C1.w*V7.x;                  \
    acc.y += C0.x*V0.y + C0.y*V1.y + C0.z*V2.y + C0.w*V3.y                   \
           + C1.x*V4.y + C1.y*V5.y + C1.z*V6.y + C1.w*V7.y;                  \
    acc.z += C0.x*V0.z + C0.y*V1.z + C0.z*V2.z + C0.w*V3.z                   \
           + C1.x*V4.z + C1.y*V5.z + C1.z*V6.z + C1.w*V7.z;                  \
    acc.w += C0.x*V0.w + C0.y*V1.w + C0.z*V2.w + C0.w*V3.w                   \
           + C1.x*V4.w + C1.y*V5.w + C1.z*V6.w + C1.w*V7.w;

__global__ __launch_bounds__(256) void k_gatherF(
    const int* __restrict__ ptr, const int* __restrict__ hist,
    const int* __restrict__ meta, const float* __restrict__ basis,
    const float* __restrict__ att, const float* __restrict__ root,
    const float* __restrict__ bias, float* __restrict__ agg)
{
    __shared__ float att_s[N_REL * N_BASES];
    int tid = threadIdx.x;
    for (int i = tid; i < N_REL * N_BASES; i += 256) att_s[i] = att[i];
    __syncthreads();

    int wid  = (int)((blockIdx.x * 256 + tid) >> 6);
    int lane = tid & 63;
    if (wid >= N_ENTITY) return;

    int half = lane >> 5;
    int l32  = lane & 31;
    int p   = ptr[wid];
    int cnt = hist[wid];
    const size_t bstride = (size_t)N_ENTITY * DIM;

    float4 acc = {0.f, 0.f, 0.f, 0.f};
    int j = 0;
    for (; j < cnt; j += 2) {
        int m0 = meta[p + j];
        bool has1 = (j + 1 < cnt);
        int m1 = has1 ? meta[p + j + 1] : m0;
        int m = half ? m1 : m0;
        float sc = (half && !has1) ? 0.0f : 1.0f;
        const float* bA = basis + (size_t)(m >> 6) * DIM + l32 * 4;
        float4 a0 = *(const float4*)(bA + 0 * bstride);
        float4 a1 = *(const float4*)(bA + 1 * bstride);
        float4 a2 = *(const float4*)(bA + 2 * bstride);
        float4 a3 = *(const float4*)(bA + 3 * bstride);
        float4 a4 = *(const float4*)(bA + 4 * bstride);
        float4 a5 = *(const float4*)(bA + 5 * bstride);
        float4 a6 = *(const float4*)(bA + 6 * bstride);
        float4 a7 = *(const float4*)(bA + 7 * bstride);
        float4 c0 = *(const float4*)(att_s + (m & 63) * N_BASES);
        float4 c1 = *(const float4*)(att_s + (m & 63) * N_BASES + 4);
        c0.x *= sc; c0.y *= sc; c0.z *= sc; c0.w *= sc;
        c1.x *= sc; c1.y *= sc; c1.z *= sc; c1.w *= sc;
        ACC8(c0, c1, a0, a1, a2, a3, a4, a5, a6, a7)
    }

    acc.x += __shfl_xor(acc.x, 32, 64);
    acc.y += __shfl_xor(acc.y, 32, 64);
    acc.z += __shfl_xor(acc.z, 32, 64);
    acc.w += __shfl_xor(acc.w, 32, 64);

    if (half == 0) {
        float inv = 1.0f / fmaxf((float)cnt, 1.0f);
        int o = wid * DIM + l32 * 4;
        float4 r  = *(const float4*)(root + o);
        float4 bb = *(const float4*)(bias + l32 * 4);
        float4 outv;
        outv.x = acc.x * inv + r.x + bb.x;
        outv.y = acc.y * inv + r.y + bb.y;
        outv.z = acc.z * inv + r.z + bb.z;
        outv.w = acc.w * inv + r.w + bb.w;
        *(float4*)(agg + o) = outv;
    }
}

// ===========================================================================
extern "C" void kernel_launch(void* const* d_in, const int* in_sizes, int n_in,
                              void* d_out, int out_size, void* d_ws, size_t ws_size,
                              hipStream_t stream)
{
    const int*   seed_ids  = (const int*)d_in[0];
    const int*   esrc      = (const int*)d_in[1];
    const int*   edst      = (const int*)d_in[2];
    const int*   etype     = (const int*)d_in[3];
    const float* basis     = (const float*)d_in[4];
    const float* att       = (const float*)d_in[5];
    const float* root      = (const float*)d_in[6];
    const float* rgcn_bias = (const float*)d_in[7];
    const float* attn_a    = (const float*)d_in[8];
    const float* attn_b    = (const float*)d_in[9];
    const float* out_bias  = (const float*)d_in[10];
    float* out = (float*)d_out;

    const size_t AGG_F  = (size_t)N_ENTITY * DIM;        // 8,239,104 words
    const size_t B16_W  = (size_t)N_ENTITY * 512;        // fp16 basis16 in words
    const size_t SLOT_W = (size_t)NPAD * CAP;            // 4,128,768

    const size_t main_words = AGG_F + B16_W + NPAD + 16 + 2 * OVF_CAP
                            + SLOT_W + 2 * BATCH * DIM + 64;
    bool big = ws_size >= main_words * 4;

    if (big) {
        float*  agg     = (float*)d_ws;
        __half* basis16 = (__half*)(agg + AGG_F);
        int*    cnt     = (int*)(agg + AGG_F + B16_W);
        int*    novf    = cnt + NPAD;
        int*    ovf     = novf + 16;
        int*    slots   = ovf + 2 * OVF_CAP;
        float*  uT      = (float*)(slots + SLOT_W);

        hipMemsetAsync(cnt, 0, (NPAD + 16) * sizeof(int), stream);
        k_prep<<<SCAT4_BLOCKS + CVT_BLOCKS, 256, 0, stream>>>(
            esrc, edst, etype, basis, basis16, cnt, novf, ovf, slots);
        k_gather16<<<(N_ENTITY * 64 + 255) / 256, 256, 0, stream>>>(
            cnt, novf, ovf, slots, basis16, att, root, rgcn_bias, agg);
        k_attn<<<BATCH, 256, 0, stream>>>(seed_ids, agg, attn_a, attn_b, uT);
        k_scores<<<(N_ENTITY + 63) / 64, 256, 0, stream>>>(agg, uT, out_bias, out);
    } else {
        // fallback: dst counting-sort + fp32 gather
        float* agg   = (float*)d_ws;
        int*   hist  = (int*)(agg + AGG_F);     // NPAD
        int*   ptr   = hist + NPAD;
        int*   work  = ptr + NPAD;
        int*   part  = work + NPAD;             // 256
        int*   meta  = part + 256;              // N_EDGES
        float* uT    = (float*)(meta + N_EDGES);

        hipMemsetAsync(hist, 0, NPAD * sizeof(int), stream);
        k_histF<<<(N_EDGES + 255) / 256, 256, 0, stream>>>(edst, hist);
        k_scan1F<<<SCAN_NB, 256, 0, stream>>>(hist, ptr, part);
        k_scan23F<<<SCAN_NB, 256, 0, stream>>>(ptr, part, work);
        k_scatterF<<<(N_EDGES + 255) / 256, 256, 0, stream>>>(
            esrc, edst, etype, work, meta);
        k_gatherF<<<(N_ENTITY * 64 + 255) / 256, 256, 0, stream>>>(
            ptr, hist, meta, basis, att, root, rgcn_bias, agg);
        k_attn<<<BATCH, 256, 0, stream>>>(seed_ids, agg, attn_a, attn_b, uT);
        k_scores<<<(N_ENTITY + 63) / 64, 256, 0, stream>>>(agg, uT, out_bias, out);
    }
}

// Round 7
// 569.004 us; speedup vs baseline: 1.1473x; 1.1227x over previous
//
#include <hip/hip_runtime.h>
#include <hip/hip_fp16.h>

#define N_ENTITY 64368
#define N_REL 40
#define DIM 128
#define N_BASES 8
#define N_EDGES 500000
#define BATCH 64
#define SEED_LEN 32
#define NROWS (BATCH * SEED_LEN)            // 2048
#define SCAN_NB ((N_ENTITY + 255) / 256)    // 252
#define NPAD (SCAN_NB * 256)                // 64512 (block-aligned entity count)

#define CAP_S 40                             // src-bucket capacity (Poisson(7.8))
#define CAP_D 40                             // dst-bucket (msg rows per dst)

struct alignas(8) half4 { __half2 lo, hi; };

// ===========================================================================
// K1 scatter: one pass over edges.
//   k_d = atomicAdd(cntd[dst]) -> msg row (dst*CAP_D + k_d), packed with type
//   k_s = atomicAdd(cnts[src]) -> slot in src bucket holding the pack
// pack (bit31=0): row<<6 | type      (row < 2^22, type < 64)
// pack (bit31=1): dst<<6 | type      (dst-overflow -> atomic-into-agg path)
// src-overflow (p ~ 1e-16): compute the message HERE, scalar (correctness).
// ===========================================================================
__global__ __launch_bounds__(256) void k_scatter(
    const int* __restrict__ esrc, const int* __restrict__ edst,
    const int* __restrict__ etype, const float* __restrict__ basis,
    const float* __restrict__ att, int* __restrict__ cnts,
    int* __restrict__ cntd, int* __restrict__ slots,
    __half* __restrict__ msg, float* __restrict__ agg)
{
    int e = blockIdx.x * 256 + threadIdx.x;
    if (e >= N_EDGES) return;
    int s = esrc[e], d = edst[e], t = etype[e];

    int kd = atomicAdd(&cntd[d], 1);
    unsigned pack;
    if (kd < CAP_D) pack = ((unsigned)(d * CAP_D + kd) << 6) | (unsigned)t;
    else            pack = 0x80000000u | ((unsigned)d << 6) | (unsigned)t;

    int ks = atomicAdd(&cnts[s], 1);
    if (ks < CAP_S) {
        slots[(size_t)s * CAP_S + ks] = (int)pack;
    } else {
        // statistically impossible; scalar correctness path
        const size_t bstride = (size_t)N_ENTITY * DIM;
        for (int dd = 0; dd < DIM; ++dd) {
            float m = 0.f;
            #pragma unroll
            for (int b = 0; b < N_BASES; ++b)
                m += att[t * N_BASES + b] * basis[b * bstride + (size_t)s * DIM + dd];
            if (kd < CAP_D)
                msg[(size_t)(d * CAP_D + kd) * DIM + dd] = __float2half(m);
            else
                unsafeAtomicAdd(&agg[(size_t)d * DIM + dd], m);
        }
    }
}

// ===========================================================================
// K2 phaseA: one HALF-WAVE per src. Loads the 8 basis rows once (streaming
// 4KB/src), then per outgoing edge computes m = sum_b c_b*row_b and writes
// the fp16 msg row directly at its dst-bucket position (scattered 256B).
// No atomics, no indirection.
// ===========================================================================
__global__ __launch_bounds__(256) void k_phaseA(
    const int* __restrict__ cnts, const int* __restrict__ slots,
    const float* __restrict__ basis, const float* __restrict__ att,
    __half* __restrict__ msg, float* __restrict__ agg)
{
    __shared__ float att_s[N_REL * N_BASES];
    int tid = threadIdx.x;
    for (int i = tid; i < N_REL * N_BASES; i += 256) att_s[i] = att[i];
    __syncthreads();

    int sid = (blockIdx.x * 256 + tid) >> 5;      // half-wave id == src id
    int l32 = tid & 31;
    if (sid >= N_ENTITY) return;
    int cnt = cnts[sid];
    if (cnt == 0) return;
    if (cnt > CAP_S) cnt = CAP_S;                 // overflow handled in scatter
    const int* sl = slots + (size_t)sid * CAP_S;

    const size_t bstride = (size_t)N_ENTITY * DIM;
    const float* bp = basis + (size_t)sid * DIM + l32 * 4;
    float4 r0 = *(const float4*)(bp + 0 * bstride);
    float4 r1 = *(const float4*)(bp + 1 * bstride);
    float4 r2 = *(const float4*)(bp + 2 * bstride);
    float4 r3 = *(const float4*)(bp + 3 * bstride);
    float4 r4 = *(const float4*)(bp + 4 * bstride);
    float4 r5 = *(const float4*)(bp + 5 * bstride);
    float4 r6 = *(const float4*)(bp + 6 * bstride);
    float4 r7 = *(const float4*)(bp + 7 * bstride);

    int j = 0;
    for (; j + 1 < cnt; j += 2) {                 // 2 edges in flight
        int pA = sl[j];
        int pB = sl[j + 1];
        const float* cAp = att_s + (pA & 63) * N_BASES;
        const float* cBp = att_s + (pB & 63) * N_BASES;
        float4 cA0 = *(const float4*)(cAp);
        float4 cA1 = *(const float4*)(cAp + 4);
        float4 cB0 = *(const float4*)(cBp);
        float4 cB1 = *(const float4*)(cBp + 4);

        float4 mA, mB;
        mA.x = cA0.x*r0.x + cA0.y*r1.x + cA0.z*r2.x + cA0.w*r3.x
             + cA1.x*r4.x + cA1.y*r5.x + cA1.z*r6.x + cA1.w*r7.x;
        mA.y = cA0.x*r0.y + cA0.y*r1.y + cA0.z*r2.y + cA0.w*r3.y
             + cA1.x*r4.y + cA1.y*r5.y + cA1.z*r6.y + cA1.w*r7.y;
        mA.z = cA0.x*r0.z + cA0.y*r1.z + cA0.z*r2.z + cA0.w*r3.z
             + cA1.x*r4.z + cA1.y*r5.z + cA1.z*r6.z + cA1.w*r7.z;
        mA.w = cA0.x*r0.w + cA0.y*r1.w + cA0.z*r2.w + cA0.w*r3.w
             + cA1.x*r4.w + cA1.y*r5.w + cA1.z*r6.w + cA1.w*r7.w;
        mB.x = cB0.x*r0.x + cB0.y*r1.x + cB0.z*r2.x + cB0.w*r3.x
             + cB1.x*r4.x + cB1.y*r5.x + cB1.z*r6.x + cB1.w*r7.x;
        mB.y = cB0.x*r0.y + cB0.y*r1.y + cB0.z*r2.y + cB0.w*r3.y
             + cB1.x*r4.y + cB1.y*r5.y + cB1.z*r6.y + cB1.w*r7.y;
        mB.z = cB0.x*r0.z + cB0.y*r1.z + cB0.z*r2.z + cB0.w*r3.z
             + cB1.x*r4.z + cB1.y*r5.z + cB1.z*r6.z + cB1.w*r7.z;
        mB.w = cB0.x*r0.w + cB0.y*r1.w + cB0.z*r2.w + cB0.w*r3.w
             + cB1.x*r4.w + cB1.y*r5.w + cB1.z*r6.w + cB1.w*r7.w;

        half4 hA, hB;
        hA.lo = __floats2half2_rn(mA.x, mA.y);
        hA.hi = __floats2half2_rn(mA.z, mA.w);
        hB.lo = __floats2half2_rn(mB.x, mB.y);
        hB.hi = __floats2half2_rn(mB.z, mB.w);
        if (pA >= 0) {
            *(half4*)(msg + ((size_t)((unsigned)pA >> 6) << 7) + (l32 << 2)) = hA;
        } else {                                  // dst overflow -> agg atomics
            int dd = (int)(((unsigned)pA >> 6) & 0x1FFFFu);
            float* ap = agg + (size_t)dd * DIM + l32 * 4;
            unsafeAtomicAdd(ap + 0, mA.x); unsafeAtomicAdd(ap + 1, mA.y);
            unsafeAtomicAdd(ap + 2, mA.z); unsafeAtomicAdd(ap + 3, mA.w);
        }
        if (pB >= 0) {
            *(half4*)(msg + ((size_t)((unsigned)pB >> 6) << 7) + (l32 << 2)) = hB;
        } else {
            int dd = (int)(((unsigned)pB >> 6) & 0x1FFFFu);
            float* ap = agg + (size_t)dd * DIM + l32 * 4;
            unsafeAtomicAdd(ap + 0, mB.x); unsafeAtomicAdd(ap + 1, mB.y);
            unsafeAtomicAdd(ap + 2, mB.z); unsafeAtomicAdd(ap + 3, mB.w);
        }
    }
    if (j < cnt) {
        int pA = sl[j];
        const float* cAp = att_s + (pA & 63) * N_BASES;
        float4 cA0 = *(const float4*)(cAp);
        float4 cA1 = *(const float4*)(cAp + 4);
        float4 mA;
        mA.x = cA0.x*r0.x + cA0.y*r1.x + cA0.z*r2.x + cA0.w*r3.x
             + cA1.x*r4.x + cA1.y*r5.x + cA1.z*r6.x + cA1.w*r7.x;
        mA.y = cA0.x*r0.y + cA0.y*r1.y + cA0.z*r2.y + cA0.w*r3.y
             + cA1.x*r4.y + cA1.y*r5.y + cA1.z*r6.y + cA1.w*r7.y;
        mA.z = cA0.x*r0.z + cA0.y*r1.z + cA0.z*r2.z + cA0.w*r3.z
             + cA1.x*r4.z + cA1.y*r5.z + cA1.z*r6.z + cA1.w*r7.z;
        mA.w = cA0.x*r0.w + cA0.y*r1.w + cA0.z*r2.w + cA0.w*r3.w
             + cA1.x*r4.w + cA1.y*r5.w + cA1.z*r6.w + cA1.w*r7.w;
        half4 hA;
        hA.lo = __floats2half2_rn(mA.x, mA.y);
        hA.hi = __floats2half2_rn(mA.z, mA.w);
        if (pA >= 0) {
            *(half4*)(msg + ((size_t)((unsigned)pA >> 6) << 7) + (l32 << 2)) = hA;
        } else {
            int dd = (int)(((unsigned)pA >> 6) & 0x1FFFFu);
            float* ap = agg + (size_t)dd * DIM + l32 * 4;
            unsafeAtomicAdd(ap + 0, mA.x); unsafeAtomicAdd(ap + 1, mA.y);
            unsafeAtomicAdd(ap + 2, mA.z); unsafeAtomicAdd(ap + 3, mA.w);
        }
    }
}

// ===========================================================================
// K3 phaseB: one wave per dst; reads its BUCKET-CONTIGUOUS fp16 msg rows
// (no index indirection); fused mean + root + bias. Adds pre-accumulated
// agg (overflow atomics; normally zero) before the mean.
// ===========================================================================
__global__ __launch_bounds__(256) void k_phaseB(
    const int* __restrict__ cntd, const __half* __restrict__ msg,
    const float* __restrict__ root, const float* __restrict__ bias,
    float* __restrict__ agg)
{
    int wid  = (int)((blockIdx.x * 256 + threadIdx.x) >> 6);
    int lane = threadIdx.x & 63;
    if (wid >= N_ENTITY) return;
    int c = cntd[wid];
    int n = (c < CAP_D) ? c : CAP_D;
    const __half2* mp = (const __half2*)msg + (size_t)wid * (CAP_D * 64) + lane;

    float ax = 0.f, ay = 0.f;
    int j = 0;
    for (; j + 3 < n; j += 4) {                   // 4 rows in flight
        float2 f0 = __half22float2(mp[(j + 0) * 64]);
        float2 f1 = __half22float2(mp[(j + 1) * 64]);
        float2 f2 = __half22float2(mp[(j + 2) * 64]);
        float2 f3 = __half22float2(mp[(j + 3) * 64]);
        ax += (f0.x + f1.x) + (f2.x + f3.x);
        ay += (f0.y + f1.y) + (f2.y + f3.y);
    }
    for (; j < n; ++j) {
        float2 f = __half22float2(mp[j * 64]);
        ax += f.x; ay += f.y;
    }

    int o = wid * DIM + lane * 2;
    float2 prev = *(const float2*)(agg + o);      // overflow atomics (usually 0)
    ax += prev.x; ay += prev.y;

    float inv = 1.0f / fmaxf((float)c, 1.0f);
    float2 r  = *(const float2*)(root + o);
    float2 bb = *(const float2*)(bias + lane * 2);
    float2 outv;
    outv.x = ax * inv + r.x + bb.x;
    outv.y = ay * inv + r.y + bb.y;
    *(float2*)(agg + o) = outv;
}

// ===========================================================================
// Fused attention: T = tanh(H@A) in registers, e = T@b, softmax, u.
// ===========================================================================
__global__ __launch_bounds__(256) void k_attn(
    const int* __restrict__ seed_ids, const float* __restrict__ nodes,
    const float* __restrict__ A, const float* __restrict__ Bv,
    float* __restrict__ uT)
{
    __shared__ float Hs[SEED_LEN * DIM];   // 16 KB
    __shared__ float ew[SEED_LEN];
    __shared__ float attw[SEED_LEN];

    int b = blockIdx.x, tid = threadIdx.x;

    for (int i = tid; i < SEED_LEN * DIM; i += 256) {
        int ss = i >> 7, d = i & 127;
        Hs[i] = nodes[(size_t)seed_ids[b * SEED_LEN + ss] * DIM + d];
    }
    __syncthreads();

    int jx = tid & 31;
    int iy = tid >> 5;
    float acc[4][4] = {{0,0,0,0},{0,0,0,0},{0,0,0,0},{0,0,0,0}};

    for (int d = 0; d < DIM; ++d) {
        const float4 a4 = *(const float4*)(A + d * DIM + jx * 4);
        float h0 = Hs[(iy * 4 + 0) * DIM + d];
        float h1 = Hs[(iy * 4 + 1) * DIM + d];
        float h2 = Hs[(iy * 4 + 2) * DIM + d];
        float h3 = Hs[(iy * 4 + 3) * DIM + d];
        acc[0][0] += h0 * a4.x; acc[0][1] += h0 * a4.y;
        acc[0][2] += h0 * a4.z; acc[0][3] += h0 * a4.w;
        acc[1][0] += h1 * a4.x; acc[1][1] += h1 * a4.y;
        acc[1][2] += h1 * a4.z; acc[1][3] += h1 * a4.w;
        acc[2][0] += h2 * a4.x; acc[2][1] += h2 * a4.y;
        acc[2][2] += h2 * a4.z; acc[2][3] += h2 * a4.w;
        acc[3][0] += h3 * a4.x; acc[3][1] += h3 * a4.y;
        acc[3][2] += h3 * a4.z; acc[3][3] += h3 * a4.w;
    }

    const float4 bv = *(const float4*)(Bv + jx * 4);
    #pragma unroll
    for (int i = 0; i < 4; ++i) {
        float pe = tanhf(acc[i][0]) * bv.x + tanhf(acc[i][1]) * bv.y
                 + tanhf(acc[i][2]) * bv.z + tanhf(acc[i][3]) * bv.w;
        pe += __shfl_xor(pe, 1, 64);
        pe += __shfl_xor(pe, 2, 64);
        pe += __shfl_xor(pe, 4, 64);
        pe += __shfl_xor(pe, 8, 64);
        pe += __shfl_xor(pe, 16, 64);
        if (jx == 0) ew[iy * 4 + i] = pe;
    }
    __syncthreads();

    if (tid == 0) {
        float mx = -1e30f;
        for (int k = 0; k < SEED_LEN; ++k) mx = fmaxf(mx, ew[k]);
        float ssum = 0.0f;
        for (int k = 0; k < SEED_LEN; ++k) {
            float v = expf(ew[k] - mx);
            attw[k] = v; ssum += v;
        }
        float inv = 1.0f / ssum;
        for (int k = 0; k < SEED_LEN; ++k) attw[k] *= inv;
    }
    __syncthreads();

    if (tid < DIM) {
        float a = 0.0f;
        for (int k = 0; k < SEED_LEN; ++k) a += attw[k] * Hs[k * DIM + tid];
        uT[tid * BATCH + b] = a;
    }
}

// ===========================================================================
// Scores: out[b][n] = u[b]·nodes[n] + out_bias[n]
// ===========================================================================
__global__ __launch_bounds__(256) void k_scores(
    const float* __restrict__ nodes, const float* __restrict__ uT,
    const float* __restrict__ out_bias, float* __restrict__ out)
{
    __shared__ float Nl[DIM * 65];

    int tid = threadIdx.x;
    int n0  = blockIdx.x * 64;

    for (int i = tid; i < 64 * DIM; i += 256) {
        int n = i >> 7, d = i & 127;
        int gn = n0 + n;
        Nl[d * 65 + n] = (gn < N_ENTITY) ? nodes[(size_t)gn * DIM + d] : 0.0f;
    }
    __syncthreads();

    int w    = __builtin_amdgcn_readfirstlane(tid >> 6);
    int lane = tid & 63;
    int b0   = w * 16;

    float acc[16];
    #pragma unroll
    for (int k = 0; k < 16; ++k) acc[k] = 0.0f;

    #pragma unroll 4
    for (int d = 0; d < DIM; ++d) {
        float nv = Nl[d * 65 + lane];
        const float* up = uT + d * BATCH + b0;
        #pragma unroll
        for (int k = 0; k < 16; ++k) acc[k] += up[k] * nv;
    }

    int gn = n0 + lane;
    if (gn < N_ENTITY) {
        float ob = out_bias[gn];
        #pragma unroll
        for (int k = 0; k < 16; ++k)
            out[(size_t)(b0 + k) * N_ENTITY + gn] = acc[k] + ob;
    }
}

// ===========================================================================
// FALLBACK PATH (tiny ws): dst counting sort + fp32 gather.
// ===========================================================================
__global__ __launch_bounds__(256) void k_histF(
    const int* __restrict__ edst, int* __restrict__ hist)
{
    int e = blockIdx.x * 256 + threadIdx.x;
    if (e < N_EDGES) atomicAdd(&hist[edst[e]], 1);
}

__global__ __launch_bounds__(256) void k_scan1F(
    const int* __restrict__ hist, int* __restrict__ ptr,
    int* __restrict__ partial)
{
    __shared__ int s[256];
    int tid = threadIdx.x;
    int gid = blockIdx.x * 256 + tid;
    int v = hist[gid];
    s[tid] = v;
    __syncthreads();
    for (int off = 1; off < 256; off <<= 1) {
        int t = (tid >= off) ? s[tid - off] : 0;
        __syncthreads();
        s[tid] += t;
        __syncthreads();
    }
    ptr[gid] = s[tid] - v;
    if (tid == 255) partial[blockIdx.x] = s[255];
}

__global__ __launch_bounds__(256) void k_scan23F(
    int* __restrict__ ptr, const int* __restrict__ partial,
    int* __restrict__ work)
{
    __shared__ int s[256];
    int tid = threadIdx.x;
    int c   = blockIdx.x;
    int sum = 0;
    for (int k = tid; k < c; k += 256) sum += partial[k];
    s[tid] = sum;
    __syncthreads();
    for (int off = 128; off > 0; off >>= 1) {
        if (tid < off) s[tid] += s[tid + off];
        __syncthreads();
    }
    int p = ptr[c * 256 + tid] + s[0];
    ptr[c * 256 + tid]  = p;
    work[c * 256 + tid] = p;
}

__global__ __launch_bounds__(256) void k_scatterF(
    const int* __restrict__ esrc, const int* __restrict__ edst,
    const int* __restrict__ etype, int* __restrict__ work,
    int* __restrict__ meta)
{
    int e = blockIdx.x * 256 + threadIdx.x;
    if (e < N_EDGES) {
        int pos = atomicAdd(&work[edst[e]], 1);
        meta[pos] = esrc[e] * 64 + etype[e];
    }
}

#define ACC8(C0, C1, V0, V1, V2, V3, V4, V5, V6, V7)                         \
    acc.x += C0.x*V0.x + C0.y*V1.x + C0.z*V2.x + C0.w*V3.x                   \
           + C1.x*V4.x + C1.y*V5.x + C1.z*V6.x + C1.w*V7.x;                  \
    acc.y += C0.x*V0.y + C0.y*V1.y + C0.z*V2.y + C0.w*V3.y                   \
           + C1.x*V4.y + C1.y*V5.y + C1.z*V6.y + C1.w*V7.y;                  \
    acc.z += C0.x*V0.z + C0.y*V1.z + C0.z*V2.z + C0.w*V3.z                   \
           + C1.x*V4.z + C1.y*V5.z + C1.z*V6.z + C1.w*V7.z;                  \
    acc.w += C0.x*V0.w + C0.y*V1.w + C0.z*V2.w + C0.w*V3.w                   \
           + C1.x*V4.w + C1.y*V5.w + C1.z*V6.w + C1.w*V7.w;

__global__ __launch_bounds__(256) void k_gatherF(
    const int* __restrict__ ptr, const int* __restrict__ hist,
    const int* __restrict__ meta, const float* __restrict__ basis,
    const float* __restrict__ att, const float* __restrict__ root,
    const float* __restrict__ bias, float* __restrict__ agg)
{
    __shared__ float att_s[N_REL * N_BASES];
    int tid = threadIdx.x;
    for (int i = tid; i < N_REL * N_BASES; i += 256) att_s[i] = att[i];
    __syncthreads();

    int wid  = (int)((blockIdx.x * 256 + tid) >> 6);
    int lane = tid & 63;
    if (wid >= N_ENTITY) return;

    int half = lane >> 5;
    int l32  = lane & 31;
    int p   = ptr[wid];
    int cnt = hist[wid];
    const size_t bstride = (size_t)N_ENTITY * DIM;

    float4 acc = {0.f, 0.f, 0.f, 0.f};
    int j = 0;
    for (; j < cnt; j += 2) {
        int m0 = meta[p + j];
        bool has1 = (j + 1 < cnt);
        int m1 = has1 ? meta[p + j + 1] : m0;
        int m = half ? m1 : m0;
        float sc = (half && !has1) ? 0.0f : 1.0f;
        const float* bA = basis + (size_t)(m >> 6) * DIM + l32 * 4;
        float4 a0 = *(const float4*)(bA + 0 * bstride);
        float4 a1 = *(const float4*)(bA + 1 * bstride);
        float4 a2 = *(const float4*)(bA + 2 * bstride);
        float4 a3 = *(const float4*)(bA + 3 * bstride);
        float4 a4 = *(const float4*)(bA + 4 * bstride);
        float4 a5 = *(const float4*)(bA + 5 * bstride);
        float4 a6 = *(const float4*)(bA + 6 * bstride);
        float4 a7 = *(const float4*)(bA + 7 * bstride);
        float4 c0 = *(const float4*)(att_s + (m & 63) * N_BASES);
        float4 c1 = *(const float4*)(att_s + (m & 63) * N_BASES + 4);
        c0.x *= sc; c0.y *= sc; c0.z *= sc; c0.w *= sc;
        c1.x *= sc; c1.y *= sc; c1.z *= sc; c1.w *= sc;
        ACC8(c0, c1, a0, a1, a2, a3, a4, a5, a6, a7)
    }

    acc.x += __shfl_xor(acc.x, 32, 64);
    acc.y += __shfl_xor(acc.y, 32, 64);
    acc.z += __shfl_xor(acc.z, 32, 64);
    acc.w += __shfl_xor(acc.w, 32, 64);

    if (half == 0) {
        float inv = 1.0f / fmaxf((float)cnt, 1.0f);
        int o = wid * DIM + l32 * 4;
        float4 r  = *(const float4*)(root + o);
        float4 bb = *(const float4*)(bias + l32 * 4);
        float4 outv;
        outv.x = acc.x * inv + r.x + bb.x;
        outv.y = acc.y * inv + r.y + bb.y;
        outv.z = acc.z * inv + r.z + bb.z;
        outv.w = acc.w * inv + r.w + bb.w;
        *(float4*)(agg + o) = outv;
    }
}

// ===========================================================================
extern "C" void kernel_launch(void* const* d_in, const int* in_sizes, int n_in,
                              void* d_out, int out_size, void* d_ws, size_t ws_size,
                              hipStream_t stream)
{
    const int*   seed_ids  = (const int*)d_in[0];
    const int*   esrc      = (const int*)d_in[1];
    const int*   edst      = (const int*)d_in[2];
    const int*   etype     = (const int*)d_in[3];
    const float* basis     = (const float*)d_in[4];
    const float* att       = (const float*)d_in[5];
    const float* root      = (const float*)d_in[6];
    const float* rgcn_bias = (const float*)d_in[7];
    const float* attn_a    = (const float*)d_in[8];
    const float* attn_b    = (const float*)d_in[9];
    const float* out_bias  = (const float*)d_in[10];
    float* out = (float*)d_out;

    const size_t AGG_F   = (size_t)N_ENTITY * DIM;            // 8,239,104 words
    const size_t SLOTS_W = (size_t)N_ENTITY * CAP_S;          // 2,574,720 words
    const size_t MSG_W   = (size_t)N_ENTITY * CAP_D * DIM / 2; // fp16 rows in words

    const size_t main_words = AGG_F + 2 * NPAD + SLOTS_W + MSG_W
                            + 2 * BATCH * DIM + 64;
    bool big = ws_size >= main_words * 4;

    if (big) {
        float*  agg   = (float*)d_ws;
        int*    cntd  = (int*)(agg + AGG_F);      // NPAD
        int*    cnts  = cntd + NPAD;              // NPAD
        int*    slots = cnts + NPAD;              // SLOTS_W
        __half* msg   = (__half*)(slots + SLOTS_W);
        float*  uT    = (float*)((int*)msg + MSG_W);

        // zero agg (overflow-atomic target) + both count arrays in one call
        hipMemsetAsync(d_ws, 0, (AGG_F + 2 * NPAD) * sizeof(int), stream);

        k_scatter<<<(N_EDGES + 255) / 256, 256, 0, stream>>>(
            esrc, edst, etype, basis, att, cnts, cntd, slots, msg, agg);
        k_phaseA<<<N_ENTITY / 8, 256, 0, stream>>>(
            cnts, slots, basis, att, msg, agg);
        k_phaseB<<<(N_ENTITY + 3) / 4, 256, 0, stream>>>(
            cntd, msg, root, rgcn_bias, agg);
        k_attn<<<BATCH, 256, 0, stream>>>(seed_ids, agg, attn_a, attn_b, uT);
        k_scores<<<(N_ENTITY + 63) / 64, 256, 0, stream>>>(agg, uT, out_bias, out);
    } else {
        // fallback: dst counting-sort + fp32 gather
        float* agg   = (float*)d_ws;
        int*   hist  = (int*)(agg + AGG_F);     // NPAD
        int*   ptr   = hist + NPAD;
        int*   work  = ptr + NPAD;
        int*   part  = work + NPAD;             // 256
        int*   meta  = part + 256;              // N_EDGES
        float* uT    = (float*)(meta + N_EDGES);

        hipMemsetAsync(hist, 0, NPAD * sizeof(int), stream);
        k_histF<<<(N_EDGES + 255) / 256, 256, 0, stream>>>(edst, hist);
        k_scan1F<<<SCAN_NB, 256, 0, stream>>>(hist, ptr, part);
        k_scan23F<<<SCAN_NB, 256, 0, stream>>>(ptr, part, work);
        k_scatterF<<<(N_EDGES + 255) / 256, 256, 0, stream>>>(
            esrc, edst, etype, work, meta);
        k_gatherF<<<(N_ENTITY * 64 + 255) / 256, 256, 0, stream>>>(
            ptr, hist, meta, basis, att, root, rgcn_bias, agg);
        k_attn<<<BATCH, 256, 0, stream>>>(seed_ids, agg, attn_a, attn_b, uT);
        k_scores<<<(N_ENTITY + 63) / 64, 256, 0, stream>>>(agg, uT, out_bias, out);
    }
}